// Round 11
// baseline (143.581 us; speedup 1.0000x reference)
//
#include <hip/hip_runtime.h>
#include <hip/hip_bf16.h>

#define BSZ  131072
#define DIM  256
#define ROWS 32                    // rows per tile
#define NT   1024                  // 16 waves; wave w owns output cols [w*16, w*16+16)
#define NBLK 512                   // 2 blocks/CU
#define TPB  (BSZ / ROWS / NBLK)   // 8 tiles per block

typedef __attribute__((ext_vector_type(8))) short bf16x8;
typedef __attribute__((ext_vector_type(4))) float f32x4;
typedef __attribute__((ext_vector_type(4))) unsigned int u32x4;
typedef __attribute__((ext_vector_type(4))) unsigned short u16x4;

// LDS map (fits 2 blocks/CU):
//  zbuf[2] : [32 rows][256 bf16 + pad] stride 528  -> 16896 each @ 0, 16896
//  obuf    : [32 rows][256 f32 + pad]  stride 1040 -> 33280     @ 33792
// total 67072
#define ZSTR  528
#define OSTR  1040
#define ZB(b) ((b) * 16896)
#define OBASE 33792

__device__ __forceinline__ unsigned short f2bf(float f) {
  unsigned u = __builtin_bit_cast(unsigned, f);
  return (unsigned short)((u + 0x7FFFu + ((u >> 16) & 1u)) >> 16);
}
__device__ __forceinline__ unsigned cvt_pk(float lo, float hi) {
  unsigned r;
  asm("v_cvt_pk_bf16_f32 %0, %1, %2" : "=v"(r) : "v"(lo), "v"(hi));
  return r;
}

// ---------------- prep: f32 W -> bf16 wT, K-major: wT[kb][j][kk] ----------------
__global__ void prep_kernel(const float* __restrict__ Wmu, const float* __restrict__ Wsd,
                            unsigned short* __restrict__ wm, unsigned short* __restrict__ wsd) {
  const int tg = blockIdx.x * 256 + threadIdx.x;   // 16384 threads
  const int j  = tg >> 6, kq = tg & 63;            // row j, k-quad (k0 = kq*4)
  const int dst = ((kq >> 3) << 13) + (j << 5) + ((kq & 7) << 2);
  f32x4 a = *(const f32x4*)(Wmu + j * 256 + kq * 4);
  f32x4 b = *(const f32x4*)(Wsd + j * 256 + kq * 4);
  u16x4 pa, pb;
#pragma unroll
  for (int e = 0; e < 4; ++e) { pa[e] = f2bf(a[e]); pb[e] = f2bf(b[e]); }
  *(u16x4*)(wm + dst)  = pa;
  *(u16x4*)(wsd + dst) = pb;
}

// ---------------- main: 2 blocks/CU, W streamed from L2, 2 barriers/tile ----------------
__global__ __launch_bounds__(NT, 8)
void main_kernel(const float* __restrict__ z,
                 const unsigned short* __restrict__ wm,
                 const unsigned short* __restrict__ wsd,
                 const float* __restrict__ bmu,
                 const float* __restrict__ bsd,
                 float* __restrict__ out,
                 float* __restrict__ partials) {
  __shared__ unsigned char smem[67072];
  __shared__ float redbuf[16];
  const int t = threadIdx.x, lane = t & 63, w = t >> 6;   // w 0..15
  const int bid = blockIdx.x;

  // ---- W fragment sources (L2-resident; per-wave load = 1KB contiguous) ----
  const int woff = (w * 16 + (lane & 15)) * 32 + (lane >> 4) * 8;   // + kb*8192
  const unsigned short* wmb = wm  + woff;
  const unsigned short* wsb = wsd + woff;

  const int colb = w * 16 + ((lane >> 4) << 2);
  const f32x4 b4m = *(const f32x4*)(bmu + colb);
  const f32x4 b4s = *(const f32x4*)(bsd + colb);

  // ---- per-thread addressing ----
  const int zrow = t >> 5, zc = t & 31;                       // stage: 8 f32 per thread
  const int zwofs = zrow * ZSTR + zc * 16;
  const int zro   = (lane & 15) * ZSTR + (lane >> 4) * 16;    // + nj*16*ZSTR + kb*64
  const int ow    = (lane & 15) * OSTR + colb * 4;            // + nj*16*OSTR

  const size_t TSTEP = (size_t)NBLK * ROWS * DIM;             // elems between my tiles
  const float* zp = z + (size_t)(bid * ROWS + zrow) * DIM + zc * 8;
  float* op = out + (size_t)(bid * ROWS) * DIM;

  float klp = 0.0f;
  f32x4 pza, pzb;

  // ---- prologue: stage z(0) into buf0; prefetch z(1) into regs ----
  {
    f32x4 a = *(const f32x4*)zp;
    f32x4 b = *(const f32x4*)(zp + 4);
    u32x4 p;
    p[0] = cvt_pk(a[0], a[1]); p[1] = cvt_pk(a[2], a[3]);
    p[2] = cvt_pk(b[0], b[1]); p[3] = cvt_pk(b[2], b[3]);
    *(u32x4*)(smem + ZB(0) + zwofs) = p;
  }
  pza = *(const f32x4*)(zp + TSTEP);
  pzb = *(const f32x4*)(zp + TSTEP + 4);
  asm volatile("s_waitcnt lgkmcnt(0)" ::: "memory");
  __builtin_amdgcn_sched_barrier(0);
  __builtin_amdgcn_s_barrier();

  // ---- tile loop ----
#pragma unroll 1
  for (int i = 0; i < TPB; ++i) {
    // A: stage z(i+1) into zbuf[(i+1)&1] (readers drained at E1(i-1))
    if (i < TPB - 1) {
      u32x4 p;
      p[0] = cvt_pk(pza[0], pza[1]); p[1] = cvt_pk(pza[2], pza[3]);
      p[2] = cvt_pk(pzb[0], pzb[1]); p[3] = cvt_pk(pzb[2], pzb[3]);
      *(u32x4*)(smem + ZB((i + 1) & 1) + zwofs) = p;
    }
    // B: prefetch z(i+2) (in flight across barriers)
    if (i < TPB - 2) {
      pza = *(const f32x4*)(zp + (size_t)(i + 2) * TSTEP);
      pzb = *(const f32x4*)(zp + (size_t)(i + 2) * TSTEP + 4);
    }

    // C: compute tile i; W fragments streamed from L2 each kb
    const unsigned char* zb = smem + ZB(i & 1);
    f32x4 am[2], al[2];
    am[0] = (f32x4)0.0f; am[1] = (f32x4)0.0f;
    al[0] = (f32x4)0.0f; al[1] = (f32x4)0.0f;
#pragma unroll
    for (int kb = 0; kb < 8; ++kb) {
      const bf16x8 wfm = *(const bf16x8*)(wmb + (kb << 13));
      const bf16x8 wfs = *(const bf16x8*)(wsb + (kb << 13));
#pragma unroll
      for (int nj = 0; nj < 2; ++nj) {
        const bf16x8 zf = *(const bf16x8*)(zb + nj * 16 * ZSTR + kb * 64 + zro);
        am[nj] = __builtin_amdgcn_mfma_f32_16x16x32_bf16(wfm, zf, am[nj], 0, 0, 0);
        al[nj] = __builtin_amdgcn_mfma_f32_16x16x32_bf16(wfs, zf, al[nj], 0, 0, 0);
      }
    }

    // D: epilogue -> obuf (F(i-1)'s reads drained at E2(i-1))
#pragma unroll
    for (int nj = 0; nj < 2; ++nj) {
      f32x4 mu4;
#pragma unroll
      for (int r = 0; r < 4; ++r) {
        float mu = fmaxf(am[nj][r] + b4m[r], 0.0f);
        float ls = fmaxf(al[nj][r] + b4s[r], 0.0f);
        float iv = __expf(-2.0f * ls);
        klp += fmaf(mu * mu, iv, iv) + 2.0f * ls;   // (1+mu^2)*iv + 2*ls; -1 folded at end
        mu4[r] = mu;
      }
      *(f32x4*)(smem + OBASE + nj * 16 * OSTR + ow) = mu4;
    }

    // E1
    asm volatile("s_waitcnt lgkmcnt(0)" ::: "memory");
    __builtin_amdgcn_sched_barrier(0);
    __builtin_amdgcn_s_barrier();

    // F: coalesced NT stores (wave stores rows 2w,2w+1; 1KB contiguous each)
#pragma unroll
    for (int rr = 0; rr < 2; ++rr) {
      const int row = w * 2 + rr;
      const f32x4 v = *(const f32x4*)(smem + OBASE + row * OSTR + lane * 16);
      __builtin_nontemporal_store(v, (f32x4*)(op + (size_t)i * TSTEP + row * DIM + lane * 4));
    }

    // E2: drain F's ds_reads so D(i+1) may overwrite obuf
    asm volatile("s_waitcnt lgkmcnt(0)" ::: "memory");
    __builtin_amdgcn_sched_barrier(0);
    __builtin_amdgcn_s_barrier();
  }

  // ---- KL reduction ----
  klp = 0.5f * (klp - (float)(TPB * 8));   // 64 elems per lane, each owes -1
#pragma unroll
  for (int off = 32; off; off >>= 1) klp += __shfl_down(klp, off);
  if (lane == 0) redbuf[w] = klp;
  __syncthreads();
  if (t == 0) {
    float s = 0.0f;
#pragma unroll
    for (int i = 0; i < 16; ++i) s += redbuf[i];
    partials[bid] = s;
  }
}

// ---------------- finalize ----------------
__global__ void fin_kernel(const float* __restrict__ partials, float* __restrict__ out) {
  __shared__ double red[256];
  red[threadIdx.x] = (double)partials[threadIdx.x] + (double)partials[threadIdx.x + 256];
  __syncthreads();
  for (int st = 128; st > 0; st >>= 1) {
    if ((int)threadIdx.x < st) red[threadIdx.x] += red[threadIdx.x + st];
    __syncthreads();
  }
  if (threadIdx.x == 0) out[(size_t)BSZ * DIM] = (float)(red[0] / (double)BSZ);
}

// ---------------- launch ----------------
// ws: [0,16384) float partials[512](+pad); [16384,+128K) wT_mu; [147456,+128K) wT_sd.
// Total 278528 B.
extern "C" void kernel_launch(void* const* d_in, const int* in_sizes, int n_in,
                              void* d_out, int out_size, void* d_ws, size_t ws_size,
                              hipStream_t stream) {
  const float* z   = (const float*)d_in[0];
  const float* Wmu = (const float*)d_in[1];
  const float* bmu = (const float*)d_in[2];
  const float* Wsd = (const float*)d_in[3];
  const float* bsd = (const float*)d_in[4];
  float* out = (float*)d_out;

  float* partials     = (float*)d_ws;
  unsigned short* wm  = (unsigned short*)((char*)d_ws + 16384);
  unsigned short* wsd = wm + DIM * DIM;

  prep_kernel<<<64, 256, 0, stream>>>(Wmu, Wsd, wm, wsd);
  main_kernel<<<NBLK, NT, 0, stream>>>(z, wm, wsd, bmu, bsd, out, partials);
  fin_kernel<<<1, 256, 0, stream>>>(partials, out);
}

// Round 12
// 116.919 us; speedup vs baseline: 1.2280x; 1.2280x over previous
//
#include <hip/hip_runtime.h>
#include <hip/hip_bf16.h>

#define BSZ  131072
#define DIM  256
#define ROWS 64                    // rows per tile
#define NT   1024                  // 16 waves; wave w owns output cols [w*16, w*16+16)
#define NBLK 256                   // persistent: 1 block/CU
#define TPB  (BSZ / ROWS / NBLK)   // 8 tiles per block

typedef __attribute__((ext_vector_type(8))) short bf16x8;
typedef __attribute__((ext_vector_type(4))) float f32x4;
typedef __attribute__((ext_vector_type(4))) unsigned int u32x4;
typedef __attribute__((ext_vector_type(4))) unsigned short u16x4;

// LDS map:
//  zbuf[2] : [64 rows][256 bf16 + pad] stride 528  -> 33792 each @ 0, 33792
//  obuf    : [64 rows][256 f32 + pad]  stride 1040 -> 66560      @ 67584
// total 134144
#define ZSTR  528
#define OSTR  1040
#define ZB(b) ((b) * 33792)
#define OBASE 67584

__device__ __forceinline__ unsigned short f2bf(float f) {
  unsigned u = __builtin_bit_cast(unsigned, f);
  return (unsigned short)((u + 0x7FFFu + ((u >> 16) & 1u)) >> 16);
}
__device__ __forceinline__ unsigned cvt_pk(float lo, float hi) {
  unsigned r;
  asm("v_cvt_pk_bf16_f32 %0, %1, %2" : "=v"(r) : "v"(lo), "v"(hi));
  return r;
}

// ---------------- prep: f32 W -> bf16 wT, K-major: wT[kb][j][kk] ----------------
__global__ void prep_kernel(const float* __restrict__ Wmu, const float* __restrict__ Wsd,
                            unsigned short* __restrict__ wm, unsigned short* __restrict__ wsd) {
  const int tg = blockIdx.x * 256 + threadIdx.x;   // 16384 threads
  const int j  = tg >> 6, kq = tg & 63;            // row j, k-quad (k0 = kq*4)
  const int dst = ((kq >> 3) << 13) + (j << 5) + ((kq & 7) << 2);
  f32x4 a = *(const f32x4*)(Wmu + j * 256 + kq * 4);
  f32x4 b = *(const f32x4*)(Wsd + j * 256 + kq * 4);
  u16x4 pa, pb;
#pragma unroll
  for (int e = 0; e < 4; ++e) { pa[e] = f2bf(a[e]); pb[e] = f2bf(b[e]); }
  *(u16x4*)(wm + dst)  = pa;
  *(u16x4*)(wsd + dst) = pb;
}

// ---------------- main: persistent, W in regs, 64-row tiles, 2 phases/tile ----------------
__global__ __launch_bounds__(NT, 4)
void main_kernel(const float* __restrict__ z,
                 const unsigned short* __restrict__ wm,
                 const unsigned short* __restrict__ wsd,
                 const float* __restrict__ bmu,
                 const float* __restrict__ bsd,
                 float* __restrict__ out,
                 float* __restrict__ partials) {
  __shared__ unsigned char smem[134144];
  __shared__ float redbuf[16];
  const int t = threadIdx.x, lane = t & 63, w = t >> 6;   // w 0..15
  const int bid = blockIdx.x;

  // ---- W fragments, loaded ONCE (wave w -> cols [w*16, w*16+16)) ----
  const int woff = (w * 16 + (lane & 15)) * 32 + (lane >> 4) * 8;
  bf16x8 wfm[8], wfs[8];
#pragma unroll
  for (int kb = 0; kb < 8; ++kb) {
    wfm[kb] = *(const bf16x8*)(wm  + (kb << 13) + woff);
    wfs[kb] = *(const bf16x8*)(wsd + (kb << 13) + woff);
  }
  const int colb = w * 16 + ((lane >> 4) << 2);
  const f32x4 b4m = *(const f32x4*)(bmu + colb);
  const f32x4 b4s = *(const f32x4*)(bsd + colb);

  // ---- per-thread addressing ----
  const int zrow = t >> 4, zc16 = t & 15;                     // stage: 16 f32 per thread
  const int zwofs = zrow * ZSTR + zc16 * 32;                  // 2x ds_write_b128 dest
  const int zro   = (lane & 15) * ZSTR + (lane >> 4) * 16;    // + nj*16*ZSTR + kb*64
  const int ow    = (lane & 15) * OSTR + colb * 4;            // + nj*16*OSTR

  const size_t TSTEP = (size_t)NBLK * ROWS * DIM;             // elems between my tiles
  const float* zp = z + (size_t)(bid * ROWS + zrow) * DIM + zc16 * 16;
  float* op = out + (size_t)(bid * ROWS) * DIM;

  float klp = 0.0f;
  f32x4 zc[4];

  // ---- prologue: stage z(0) into buf0 ----
#pragma unroll
  for (int j = 0; j < 4; ++j) zc[j] = *(const f32x4*)(zp + j * 4);
  {
    u32x4 p0, p1;
    p0[0] = cvt_pk(zc[0][0], zc[0][1]); p0[1] = cvt_pk(zc[0][2], zc[0][3]);
    p0[2] = cvt_pk(zc[1][0], zc[1][1]); p0[3] = cvt_pk(zc[1][2], zc[1][3]);
    p1[0] = cvt_pk(zc[2][0], zc[2][1]); p1[1] = cvt_pk(zc[2][2], zc[2][3]);
    p1[2] = cvt_pk(zc[3][0], zc[3][1]); p1[3] = cvt_pk(zc[3][2], zc[3][3]);
    *(u32x4*)(smem + ZB(0) + zwofs) = p0;
    *(u32x4*)(smem + ZB(0) + zwofs + 16) = p1;
  }
  asm volatile("s_waitcnt lgkmcnt(0)" ::: "memory");
  __builtin_amdgcn_sched_barrier(0);
  __builtin_amdgcn_s_barrier();

  // ---- tile loop: P1 {prefetch, compute, epilogue} E1 | P2 {store, stage} E2 ----
#pragma unroll 1
  for (int i = 0; i < TPB; ++i) {
    // B: issue global loads of z(i+1) (consumed in P2)
    if (i < TPB - 1) {
#pragma unroll
      for (int j = 0; j < 4; ++j)
        zc[j] = *(const f32x4*)(zp + (size_t)(i + 1) * TSTEP + j * 4);
    }

    // C: compute tile i from zbuf[i&1]
    const unsigned char* zb = smem + ZB(i & 1);
    f32x4 am[4], al[4];
#pragma unroll
    for (int nj = 0; nj < 4; ++nj) { am[nj] = (f32x4)0.0f; al[nj] = (f32x4)0.0f; }
#pragma unroll
    for (int kb = 0; kb < 8; ++kb)
#pragma unroll
      for (int nj = 0; nj < 4; ++nj) {
        const bf16x8 zf = *(const bf16x8*)(zb + nj * 16 * ZSTR + kb * 64 + zro);
        am[nj] = __builtin_amdgcn_mfma_f32_16x16x32_bf16(wfm[kb], zf, am[nj], 0, 0, 0);
        al[nj] = __builtin_amdgcn_mfma_f32_16x16x32_bf16(wfs[kb], zf, al[nj], 0, 0, 0);
      }

    // D: epilogue -> obuf
#pragma unroll
    for (int nj = 0; nj < 4; ++nj) {
      f32x4 mu4;
#pragma unroll
      for (int r = 0; r < 4; ++r) {
        float mu = fmaxf(am[nj][r] + b4m[r], 0.0f);
        float ls = fmaxf(al[nj][r] + b4s[r], 0.0f);
        float iv = __expf(-2.0f * ls);
        klp += fmaf(mu * mu, iv, iv) + 2.0f * ls;   // (1+mu^2)*iv + 2*ls; -1 folded at end
        mu4[r] = mu;
      }
      *(f32x4*)(smem + OBASE + nj * 16 * OSTR + ow) = mu4;
    }

    // E1: obuf complete; zbuf[i&1] reads retired
    asm volatile("s_waitcnt lgkmcnt(0)" ::: "memory");
    __builtin_amdgcn_sched_barrier(0);
    __builtin_amdgcn_s_barrier();

    // F: coalesced NT stores (wave stores rows 4w..4w+3; 1KB contiguous each)
#pragma unroll
    for (int rr = 0; rr < 4; ++rr) {
      const int row = w * 4 + rr;
      const f32x4 v = *(const f32x4*)(smem + OBASE + row * OSTR + lane * 16);
      __builtin_nontemporal_store(v, (f32x4*)(op + (size_t)i * TSTEP + row * DIM + lane * 4));
    }

    // A: stage z(i+1) into zbuf[(i+1)&1]
    if (i < TPB - 1) {
      u32x4 p0, p1;
      p0[0] = cvt_pk(zc[0][0], zc[0][1]); p0[1] = cvt_pk(zc[0][2], zc[0][3]);
      p0[2] = cvt_pk(zc[1][0], zc[1][1]); p0[3] = cvt_pk(zc[1][2], zc[1][3]);
      p1[0] = cvt_pk(zc[2][0], zc[2][1]); p1[1] = cvt_pk(zc[2][2], zc[2][3]);
      p1[2] = cvt_pk(zc[3][0], zc[3][1]); p1[3] = cvt_pk(zc[3][2], zc[3][3]);
      *(u32x4*)(smem + ZB((i + 1) & 1) + zwofs) = p0;
      *(u32x4*)(smem + ZB((i + 1) & 1) + zwofs + 16) = p1;
    }

    // E2: z(i+1) staged; obuf reads retired -> D(i+1) may overwrite
    asm volatile("s_waitcnt lgkmcnt(0)" ::: "memory");
    __builtin_amdgcn_sched_barrier(0);
    __builtin_amdgcn_s_barrier();
  }

  // ---- KL reduction ----
  klp = 0.5f * (klp - (float)(TPB * 16));   // 128 elems per lane, each owes -1
#pragma unroll
  for (int off = 32; off; off >>= 1) klp += __shfl_down(klp, off);
  if (lane == 0) redbuf[w] = klp;
  __syncthreads();
  if (t == 0) {
    float s = 0.0f;
#pragma unroll
    for (int i = 0; i < 16; ++i) s += redbuf[i];
    partials[bid] = s;
  }
}

// ---------------- finalize ----------------
__global__ void fin_kernel(const float* __restrict__ partials, float* __restrict__ out) {
  __shared__ double red[256];
  red[threadIdx.x] = (double)partials[threadIdx.x];
  __syncthreads();
  for (int st = 128; st > 0; st >>= 1) {
    if ((int)threadIdx.x < st) red[threadIdx.x] += red[threadIdx.x + st];
    __syncthreads();
  }
  if (threadIdx.x == 0) out[(size_t)BSZ * DIM] = (float)(red[0] / (double)BSZ);
}

// ---------------- launch ----------------
// ws: [0,16384) float partials[256](+pad); [16384,+128K) wT_mu; [147456,+128K) wT_sd.
// Total 278528 B.
extern "C" void kernel_launch(void* const* d_in, const int* in_sizes, int n_in,
                              void* d_out, int out_size, void* d_ws, size_t ws_size,
                              hipStream_t stream) {
  const float* z   = (const float*)d_in[0];
  const float* Wmu = (const float*)d_in[1];
  const float* bmu = (const float*)d_in[2];
  const float* Wsd = (const float*)d_in[3];
  const float* bsd = (const float*)d_in[4];
  float* out = (float*)d_out;

  float* partials     = (float*)d_ws;
  unsigned short* wm  = (unsigned short*)((char*)d_ws + 16384);
  unsigned short* wsd = wm + DIM * DIM;

  prep_kernel<<<64, 256, 0, stream>>>(Wmu, Wsd, wm, wsd);
  main_kernel<<<NBLK, NT, 0, stream>>>(z, wm, wsd, bmu, bsd, out, partials);
  fin_kernel<<<1, 256, 0, stream>>>(partials, out);
}

// Round 13
// 79.253 us; speedup vs baseline: 1.8117x; 1.4753x over previous
//
#include <hip/hip_runtime.h>
#include <hip/hip_bf16.h>

#define BSZ  131072
#define DIM  256
#define ROWS 32
#define NT   512                   // 8 waves; wave w owns 16 cols of this block's 128-col half
#define NBLK 512                   // 2 blocks/CU (two independent barrier domains)
#define TPB  16                    // tiles per block: 131072/32/256 row-groups

typedef __attribute__((ext_vector_type(8))) short bf16x8;
typedef __attribute__((ext_vector_type(4))) float f32x4;
typedef __attribute__((ext_vector_type(4))) unsigned int u32x4;
typedef __attribute__((ext_vector_type(4))) unsigned short u16x4;

// LDS map (49664 B -> 2 blocks/CU easily):
//  zbuf[2] : [32 rows][32 slots x16B] stride 512, slot ^= (row&7)  -> 16384 each @ 0, 16384
//  obuf    : [32 rows][128 f32 + 16B pad] stride 528               -> 16896 @ 32768
#define ZSTRD 512
#define OSTR  528
#define ZB(b) ((b) * 16384)
#define OBASE 32768

__device__ __forceinline__ unsigned short f2bf(float f) {
  unsigned u = __builtin_bit_cast(unsigned, f);
  return (unsigned short)((u + 0x7FFFu + ((u >> 16) & 1u)) >> 16);
}
__device__ __forceinline__ unsigned cvt_pk(float lo, float hi) {
  unsigned r;
  asm("v_cvt_pk_bf16_f32 %0, %1, %2" : "=v"(r) : "v"(lo), "v"(hi));
  return r;
}

// ---------------- prep: f32 W -> bf16 wT, K-major: wT[kb][j][kk] ----------------
__global__ void prep_kernel(const float* __restrict__ Wmu, const float* __restrict__ Wsd,
                            unsigned short* __restrict__ wm, unsigned short* __restrict__ wsd) {
  const int tg = blockIdx.x * 256 + threadIdx.x;   // 16384 threads
  const int j  = tg >> 6, kq = tg & 63;            // row j, k-quad (k0 = kq*4)
  const int dst = ((kq >> 3) << 13) + (j << 5) + ((kq & 7) << 2);
  f32x4 a = *(const f32x4*)(Wmu + j * 256 + kq * 4);
  f32x4 b = *(const f32x4*)(Wsd + j * 256 + kq * 4);
  u16x4 pa, pb;
#pragma unroll
  for (int e = 0; e < 4; ++e) { pa[e] = f2bf(a[e]); pb[e] = f2bf(b[e]); }
  *(u16x4*)(wm + dst)  = pa;
  *(u16x4*)(wsd + dst) = pb;
}

// ---------------- main: col-split 512-thread blocks, W in regs, swizzled z LDS ----------------
__global__ __launch_bounds__(NT, 4)
void main_kernel(const float* __restrict__ z,
                 const unsigned short* __restrict__ wm,
                 const unsigned short* __restrict__ wsd,
                 const float* __restrict__ bmu,
                 const float* __restrict__ bsd,
                 float* __restrict__ out,
                 float* __restrict__ partials) {
  __shared__ unsigned char smem[49664];
  __shared__ float redbuf[8];
  const int t = threadIdx.x, lane = t & 63, w = t >> 6;   // w 0..7
  const int bid = blockIdx.x;
  const int ch  = bid & 1;                 // col half: cols [ch*128, ch*128+128)
  const int rg0 = bid >> 1;                // starting row-group (0..255)

  // ---- W fragments, loaded ONCE (wave w -> global cols ch*128 + w*16 ..+16) ----
  const int gcol0 = ch * 128 + w * 16;
  const int woff = (gcol0 + (lane & 15)) * 32 + (lane >> 4) * 8;
  bf16x8 wfm[8], wfs[8];
#pragma unroll
  for (int kb = 0; kb < 8; ++kb) {
    wfm[kb] = *(const bf16x8*)(wm  + (kb << 13) + woff);
    wfs[kb] = *(const bf16x8*)(wsd + (kb << 13) + woff);
  }
  const int gcolb = gcol0 + ((lane >> 4) << 2);       // bias/global col base
  const int lcolb = w * 16 + ((lane >> 4) << 2);      // local col base (0..127)
  const f32x4 b4m = *(const f32x4*)(bmu + gcolb);
  const f32x4 b4s = *(const f32x4*)(bsd + gcolb);

  // ---- z staging addressing: thread stages 16 f32 (row t>>4, cols (t&15)*16..) ----
  const int zrow = t >> 4, zc16 = t & 15;
  const size_t TSTEP = (size_t)256 * ROWS * DIM;      // elems between my tiles
  const float* zp = z + (size_t)(rg0 * ROWS + zrow) * DIM + zc16 * 16;
  float* op = out + (size_t)(rg0 * ROWS) * DIM;

  // z fragment read: row R=nj*16+(lane&15); slot=(kb*4+g)^(lane&7), g=lane>>4
  const int zrbase = (lane & 15) * ZSTRD;
  const int g = lane >> 4, r7 = lane & 7;

  // obuf epilogue write offset
  const int ow = (lane & 15) * OSTR + lcolb * 4;      // + nj*16*OSTR

  float klp = 0.0f;
  f32x4 zc[4];

  auto stage = [&](int i, int buf) {
#pragma unroll
    for (int j = 0; j < 4; ++j) {
      u32x4 p;
      p[0] = cvt_pk(zc[j][0], zc[j][1]); p[1] = cvt_pk(zc[j][2], zc[j][3]);
      // one u32x2 per f32x4: 8 bf16 = 16B = one slot
      const int slot = (zc16 * 4 + j) ^ (zrow & 7);
      *(unsigned long long*)(smem + ZB(buf) + zrow * ZSTRD + slot * 16) =
          *(unsigned long long*)&p;  // low 8B: two u32 = 4 bf16... (see note below)
      // NOTE: 16B slot needs 8 bf16 = 4 u32; build full u32x4 from 2 f32x4 halves
      (void)p;
    }
  };
  (void)stage; // replaced by explicit code below (16B per slot needs two f32x4)

  // ---- prologue: load z(0), stage into buf0 ----
#pragma unroll
  for (int j = 0; j < 4; ++j) zc[j] = *(const f32x4*)(zp + j * 4);
#pragma unroll
  for (int j = 0; j < 2; ++j) {
    u32x4 p;
    p[0] = cvt_pk(zc[2*j][0], zc[2*j][1]);   p[1] = cvt_pk(zc[2*j][2], zc[2*j][3]);
    p[2] = cvt_pk(zc[2*j+1][0], zc[2*j+1][1]); p[3] = cvt_pk(zc[2*j+1][2], zc[2*j+1][3]);
    const int slot = (zc16 * 2 + j) ^ (zrow & 7);
    *(u32x4*)(smem + ZB(0) + zrow * ZSTRD + slot * 16) = p;
  }
  asm volatile("s_waitcnt lgkmcnt(0)" ::: "memory");
  __builtin_amdgcn_sched_barrier(0);
  __builtin_amdgcn_s_barrier();

  // ---- tile loop: P1{prefetch z, compute, epilogue} E1 | P2{store, stage} E2 ----
#pragma unroll 1
  for (int i = 0; i < TPB; ++i) {
    // B: global prefetch z(i+1) into regs (in flight through P1)
    if (i < TPB - 1) {
#pragma unroll
      for (int j = 0; j < 4; ++j)
        zc[j] = *(const f32x4*)(zp + (size_t)(i + 1) * TSTEP + j * 4);
    }

    // C: compute tile i from zbuf[i&1]
    const unsigned char* zb = smem + ZB(i & 1);
    f32x4 am[2], al[2];
    am[0] = (f32x4)0.0f; am[1] = (f32x4)0.0f;
    al[0] = (f32x4)0.0f; al[1] = (f32x4)0.0f;
#pragma unroll
    for (int kb = 0; kb < 8; ++kb) {
      const int slot = ((kb << 2) | g) ^ r7;
#pragma unroll
      for (int nj = 0; nj < 2; ++nj) {
        const bf16x8 zf = *(const bf16x8*)(zb + nj * 16 * ZSTRD + zrbase + slot * 16);
        am[nj] = __builtin_amdgcn_mfma_f32_16x16x32_bf16(wfm[kb], zf, am[nj], 0, 0, 0);
        al[nj] = __builtin_amdgcn_mfma_f32_16x16x32_bf16(wfs[kb], zf, al[nj], 0, 0, 0);
      }
    }

    // D: epilogue -> obuf
#pragma unroll
    for (int nj = 0; nj < 2; ++nj) {
      f32x4 mu4;
#pragma unroll
      for (int r = 0; r < 4; ++r) {
        float mu = fmaxf(am[nj][r] + b4m[r], 0.0f);
        float ls = fmaxf(al[nj][r] + b4s[r], 0.0f);
        float iv = __expf(-2.0f * ls);
        klp += fmaf(mu * mu, iv, iv) + 2.0f * ls;   // (1+mu^2)*iv + 2*ls; -1 folded at end
        mu4[r] = mu;
      }
      *(f32x4*)(smem + OBASE + nj * 16 * OSTR + ow) = mu4;
    }

    // E1: obuf complete; zbuf[i&1] reads retired
    asm volatile("s_waitcnt lgkmcnt(0)" ::: "memory");
    __builtin_amdgcn_sched_barrier(0);
    __builtin_amdgcn_s_barrier();

    // F: stores (wave w: rows 4w..4w+3; per instr 2 rows x 512B contiguous)
#pragma unroll
    for (int rr = 0; rr < 2; ++rr) {
      const int row = w * 4 + rr * 2 + (lane >> 5);
      const f32x4 v = *(const f32x4*)(smem + OBASE + row * OSTR + (lane & 31) * 16);
      __builtin_nontemporal_store(v,
          (f32x4*)(op + (size_t)i * TSTEP + row * DIM + ch * 128 + (lane & 31) * 4));
    }

    // A: stage z(i+1) into zbuf[(i+1)&1]
    if (i < TPB - 1) {
#pragma unroll
      for (int j = 0; j < 2; ++j) {
        u32x4 p;
        p[0] = cvt_pk(zc[2*j][0], zc[2*j][1]);     p[1] = cvt_pk(zc[2*j][2], zc[2*j][3]);
        p[2] = cvt_pk(zc[2*j+1][0], zc[2*j+1][1]); p[3] = cvt_pk(zc[2*j+1][2], zc[2*j+1][3]);
        const int slot = (zc16 * 2 + j) ^ (zrow & 7);
        *(u32x4*)(smem + ZB((i + 1) & 1) + zrow * ZSTRD + slot * 16) = p;
      }
    }

    // E2: z(i+1) staged; obuf reads retired
    asm volatile("s_waitcnt lgkmcnt(0)" ::: "memory");
    __builtin_amdgcn_sched_barrier(0);
    __builtin_amdgcn_s_barrier();
  }

  // ---- KL reduction ----
  klp = 0.5f * (klp - (float)(TPB * 8));   // 128 elems per lane, each owes -1
#pragma unroll
  for (int off = 32; off; off >>= 1) klp += __shfl_down(klp, off);
  if (lane == 0) redbuf[w] = klp;
  __syncthreads();
  if (t == 0) {
    float s = 0.0f;
#pragma unroll
    for (int i = 0; i < 8; ++i) s += redbuf[i];
    partials[bid] = s;
  }
}

// ---------------- finalize ----------------
__global__ void fin_kernel(const float* __restrict__ partials, float* __restrict__ out) {
  __shared__ double red[256];
  red[threadIdx.x] = (double)partials[threadIdx.x] + (double)partials[threadIdx.x + 256];
  __syncthreads();
  for (int st = 128; st > 0; st >>= 1) {
    if ((int)threadIdx.x < st) red[threadIdx.x] += red[threadIdx.x + st];
    __syncthreads();
  }
  if (threadIdx.x == 0) out[(size_t)BSZ * DIM] = (float)(red[0] / (double)BSZ);
}

// ---------------- launch ----------------
// ws: [0,16384) float partials[512](+pad); [16384,+128K) wT_mu; [147456,+128K) wT_sd.
// Total 278528 B.
extern "C" void kernel_launch(void* const* d_in, const int* in_sizes, int n_in,
                              void* d_out, int out_size, void* d_ws, size_t ws_size,
                              hipStream_t stream) {
  const float* z   = (const float*)d_in[0];
  const float* Wmu = (const float*)d_in[1];
  const float* bmu = (const float*)d_in[2];
  const float* Wsd = (const float*)d_in[3];
  const float* bsd = (const float*)d_in[4];
  float* out = (float*)d_out;

  float* partials     = (float*)d_ws;
  unsigned short* wm  = (unsigned short*)((char*)d_ws + 16384);
  unsigned short* wsd = wm + DIM * DIM;

  prep_kernel<<<64, 256, 0, stream>>>(Wmu, Wsd, wm, wsd);
  main_kernel<<<NBLK, NT, 0, stream>>>(z, wm, wsd, bmu, bsd, out, partials);
  fin_kernel<<<1, 256, 0, stream>>>(partials, out);
}